// Round 4
// baseline (63102.759 us; speedup 1.0000x reference)
//
#include <hip/hip_runtime.h>
#include <hip/hip_bf16.h>

// ---------------------------------------------------------------------------
// 3-layer original-paper GRU, B=128, T=128, I=512, H={512,1024,2048}.
// Round 4: R3 architecture made memory-safe (R3 overflowed d_ws: ~324 MB).
//  - Input projections hoisted in TC-timestep chunks (adaptive TC per layer,
//    chosen to fit ws_size; worst-case peak ~99 MB).
//  - Phased stack allocator: per-layer scratch (casts + GI chunk) reused
//    across layer phases; persistent region holds h state + h histories.
//  - Scan: barrier-free register-direct wave GEMMs (each wave owns 128x16 of
//    the hidden GEMM; A is L1/L2-resident h, B streams Whh rows once).
// ---------------------------------------------------------------------------

typedef __attribute__((ext_vector_type(8))) short s16x8;
typedef __attribute__((ext_vector_type(4))) float f32x4;

#define LLDS16(g, s)                                                          \
  __builtin_amdgcn_global_load_lds(                                           \
      (const __attribute__((address_space(1))) void*)(g),                     \
      (__attribute__((address_space(3))) void*)(s), 16, 0, 0)

__device__ __forceinline__ unsigned short f2b(float f) {
  unsigned int u = __float_as_uint(f);
  unsigned int r = (u + 0x7FFFu + ((u >> 16) & 1u)) >> 16;
  return (unsigned short)r;
}
__device__ __forceinline__ float b2f(unsigned short u) {
  return __uint_as_float(((unsigned int)u) << 16);
}
__device__ __forceinline__ float sigmoidf_(float x) {
  return 1.0f / (1.0f + __expf(-x));
}
__device__ __forceinline__ float tanhf_(float x) {
  x = fminf(fmaxf(x, -15.0f), 15.0f);
  float e = __expf(-2.0f * x);
  return (1.0f - e) / (1.0f + e);
}

// ======================= hoist GEMM (R2 core, 64x64 tile, BK=128) ==========
// Stage 64x128 bf16 tile, XOR-swizzled. Virtual row rv maps to physical row
// phys = (rv>>sh)*per + base + (rv&msk)   (identity: sh=31, per=0, msk=max).
__device__ __forceinline__ void issue_tile_m(
    const unsigned short* __restrict__ g, size_t ld, int rvbase, int sh,
    int per, int base, int msk, int k0, unsigned short* lds) {
  const int tid = threadIdx.x;
  const int wave = tid >> 6, lane = tid & 63;
#pragma unroll
  for (int j = 0; j < 4; ++j) {
    int s = wave * 4 + j;
    int rloc = s * 4 + (lane >> 4);  // tile-local row 0..63
    int rv = rvbase + rloc;
    int phys = ((rv >> sh) * per) + base + (rv & msk);
    int cg = (lane & 15) ^ (rloc & 15);
    LLDS16(g + (size_t)phys * ld + k0 + cg * 8, lds + s * 512);
  }
}

__device__ __forceinline__ void compute_chunk(const unsigned short* Ab,
                                              const unsigned short* Bb,
                                              f32x4 acc[2][2]) {
  const int tid = threadIdx.x;
  const int wave = tid >> 6, lane = tid & 63;
  const int wm = wave >> 1, wn = wave & 1, quad = lane >> 4, l16 = lane & 15;
#pragma unroll
  for (int ks = 0; ks < 4; ++ks) {
    s16x8 av[2], bv[2];
#pragma unroll
    for (int mi = 0; mi < 2; ++mi) {
      int r = wm * 32 + mi * 16 + l16;
      av[mi] = *(const s16x8*)(Ab + (size_t)r * 128 +
                               (((ks * 4 + quad) ^ (r & 15)) * 8));
    }
#pragma unroll
    for (int ni = 0; ni < 2; ++ni) {
      int r = wn * 32 + ni * 16 + l16;
      bv[ni] = *(const s16x8*)(Bb + (size_t)r * 128 +
                               (((ks * 4 + quad) ^ (r & 15)) * 8));
    }
#pragma unroll
    for (int mi = 0; mi < 2; ++mi)
#pragma unroll
      for (int ni = 0; ni < 2; ++ni)
        acc[mi][ni] = __builtin_amdgcn_mfma_f32_16x16x32_bf16(
            av[mi], bv[ni], acc[mi][ni], 0, 0, 0);
  }
}

// C[rv, col] = A[phys(rv), :] @ B^T + bias, bf16 out. Grid (Mv/64, N/64).
__global__ __launch_bounds__(256) void hoist_kernel(
    const unsigned short* __restrict__ A, int ldA, int ash, int aper,
    int abase, int amsk, const unsigned short* __restrict__ B, int K,
    const float* __restrict__ bias, unsigned short* __restrict__ C, int N) {
  __shared__ unsigned short As[2 * 8192], Bs[2 * 8192];
  f32x4 acc[2][2] = {};
  const int bm = blockIdx.x, bn = blockIdx.y;
  const int total = K >> 7;
  issue_tile_m(A, (size_t)ldA, bm * 64, ash, aper, abase, amsk, 0, As);
  issue_tile_m(B, (size_t)K, bn * 64, 31, 0, 0, 0x7FFFFFFF, 0, Bs);
  for (int c = 0; c < total; ++c) {
    __syncthreads();
    if (c + 1 < total) {
      int k0 = (c + 1) << 7, buf = (c + 1) & 1;
      issue_tile_m(A, (size_t)ldA, bm * 64, ash, aper, abase, amsk, k0,
                   As + buf * 8192);
      issue_tile_m(B, (size_t)K, bn * 64, 31, 0, 0, 0x7FFFFFFF, k0,
                   Bs + buf * 8192);
    }
    compute_chunk(As + (c & 1) * 8192, Bs + (c & 1) * 8192, acc);
  }
  const int tid = threadIdx.x, wave = tid >> 6, lane = tid & 63;
  const int wm = wave >> 1, wn = wave & 1, quad = lane >> 4, l16 = lane & 15;
#pragma unroll
  for (int mi = 0; mi < 2; ++mi)
#pragma unroll
    for (int ni = 0; ni < 2; ++ni) {
      int col = bn * 64 + wn * 32 + ni * 16 + l16;
      float bv = bias[col];
#pragma unroll
      for (int r = 0; r < 4; ++r) {
        int rv = bm * 64 + wm * 32 + mi * 16 + quad * 4 + r;
        C[(size_t)rv * N + col] = f2b(acc[mi][ni][r] + bv);
      }
    }
}

// ======================= scan kernels (register-direct wave GEMM) ==========
template <int K>
__global__ __launch_bounds__(256) void zr_kernel(
    const unsigned short* __restrict__ hb,   // [128,K] bf16 (K==H)
    const unsigned short* __restrict__ Wzr,  // [2H,K] bf16
    const unsigned short* __restrict__ gi,   // row r -> gi[r*giStride + col]
    size_t giStride, const float* __restrict__ hf, float* __restrict__ zbuf,
    unsigned short* __restrict__ rh) {
  const int tid = threadIdx.x;
  const int wave = tid >> 6, lane = tid & 63;
  const int l16 = lane & 15, quad = lane >> 4;
  const int bn = blockIdx.x * 4 + wave;
  const int H = K;
  f32x4 acc[8] = {{0.f, 0.f, 0.f, 0.f}, {0.f, 0.f, 0.f, 0.f},
                  {0.f, 0.f, 0.f, 0.f}, {0.f, 0.f, 0.f, 0.f},
                  {0.f, 0.f, 0.f, 0.f}, {0.f, 0.f, 0.f, 0.f},
                  {0.f, 0.f, 0.f, 0.f}, {0.f, 0.f, 0.f, 0.f}};
  const unsigned short* brow = Wzr + ((size_t)bn * 16 + l16) * K;
#pragma unroll 8
  for (int k = 0; k < K; k += 32) {
    s16x8 b = *(const s16x8*)(brow + k + quad * 8);
#pragma unroll
    for (int mi = 0; mi < 8; ++mi) {
      s16x8 a = *(const s16x8*)(hb + (size_t)(mi * 16 + l16) * K + k + quad * 8);
      acc[mi] = __builtin_amdgcn_mfma_f32_16x16x32_bf16(a, b, acc[mi], 0, 0, 0);
    }
  }
  const int col = bn * 16 + l16;
  const bool isz = col < H;  // wave-uniform (16 | H)
  const int j = isz ? col : col - H;
#pragma unroll
  for (int mi = 0; mi < 8; ++mi)
#pragma unroll
    for (int r = 0; r < 4; ++r) {
      int row = mi * 16 + quad * 4 + r;
      float v = acc[mi][r] + b2f(gi[(size_t)row * giStride + col]);
      float s = sigmoidf_(v);
      if (isz)
        zbuf[(size_t)row * H + j] = s;
      else
        rh[(size_t)row * H + j] = f2b(s * hf[(size_t)row * H + j]);
    }
}

template <int K>
__global__ __launch_bounds__(256) void n_kernel(
    const unsigned short* __restrict__ rh,   // [128,K] bf16 (K==H)
    const unsigned short* __restrict__ Wn,   // [H,K] bf16 (pre-offset)
    const unsigned short* __restrict__ gi,   // pre-offset by 2H cols
    size_t giStride, const float* __restrict__ zbuf, float* __restrict__ hf,
    unsigned short* __restrict__ hb, unsigned short* __restrict__ hall,
    float* __restrict__ out, int out_off, const float* __restrict__ mask,
    int t) {
  const int tid = threadIdx.x;
  const int wave = tid >> 6, lane = tid & 63;
  const int l16 = lane & 15, quad = lane >> 4;
  const int bn = blockIdx.x * 4 + wave;
  const int H = K;
  f32x4 acc[8] = {{0.f, 0.f, 0.f, 0.f}, {0.f, 0.f, 0.f, 0.f},
                  {0.f, 0.f, 0.f, 0.f}, {0.f, 0.f, 0.f, 0.f},
                  {0.f, 0.f, 0.f, 0.f}, {0.f, 0.f, 0.f, 0.f},
                  {0.f, 0.f, 0.f, 0.f}, {0.f, 0.f, 0.f, 0.f}};
  const unsigned short* brow = Wn + ((size_t)bn * 16 + l16) * K;
#pragma unroll 8
  for (int k = 0; k < K; k += 32) {
    s16x8 b = *(const s16x8*)(brow + k + quad * 8);
#pragma unroll
    for (int mi = 0; mi < 8; ++mi) {
      s16x8 a = *(const s16x8*)(rh + (size_t)(mi * 16 + l16) * K + k + quad * 8);
      acc[mi] = __builtin_amdgcn_mfma_f32_16x16x32_bf16(a, b, acc[mi], 0, 0, 0);
    }
  }
  const int col = bn * 16 + l16;
#pragma unroll
  for (int mi = 0; mi < 8; ++mi)
#pragma unroll
    for (int r = 0; r < 4; ++r) {
      int row = mi * 16 + quad * 4 + r;
      float v = acc[mi][r] + b2f(gi[(size_t)row * giStride + col]);
      float nv = tanhf_(v);
      size_t idx = (size_t)row * H + col;
      float z = zbuf[idx];
      float hn = (1.0f - z) * nv + z * hf[idx];
      hf[idx] = hn;
      hb[idx] = f2b(hn);
      if (hall) hall[(size_t)(t * 128 + row) * H + col] = f2b(hn);
      out[(size_t)row * 3584 + out_off + col] += mask[row * 128 + t] * hn;
    }
}

__global__ void cast_kernel(const float* __restrict__ src,
                            unsigned short* __restrict__ dst, int n) {
  int i = blockIdx.x * 256 + threadIdx.x;
  if (i < n) dst[i] = f2b(src[i]);
}

extern "C" void kernel_launch(void* const* d_in, const int* in_sizes, int n_in,
                              void* d_out, int out_size, void* d_ws,
                              size_t ws_size, hipStream_t stream) {
  const int B = 128, T = 128, I = 512;
  const int Hs[3] = {512, 1024, 2048};
  const int outoff[3] = {0, 512, 1536};

  const float* x = (const float*)d_in[0];
  const float* mask = (const float*)d_in[1];
  const float* Wih[3] = {(const float*)d_in[2], (const float*)d_in[5],
                         (const float*)d_in[8]};
  const float* Whh[3] = {(const float*)d_in[3], (const float*)d_in[6],
                         (const float*)d_in[9]};
  const float* bias[3] = {(const float*)d_in[4], (const float*)d_in[7],
                          (const float*)d_in[10]};

  char* ws = (char*)d_ws;
  size_t off = 0;
  auto alloc = [&](size_t bytes) -> void* {
    void* p = ws + off;
    off = (off + bytes + 255) & ~(size_t)255;
    return p;
  };
  auto pad = [](size_t b) { return (b + 255) & ~(size_t)255; };

  // ---- persistent region ----
  size_t hstart = off;
  float* hf[3];
  unsigned short* hb[3];
  for (int l = 0; l < 3; ++l) hf[l] = (float*)alloc((size_t)B * Hs[l] * 4);
  for (int l = 0; l < 3; ++l)
    hb[l] = (unsigned short*)alloc((size_t)B * Hs[l] * 2);
  size_t hend = off;
  float* zbuf = (float*)alloc((size_t)B * 2048 * 4);
  unsigned short* rh = (unsigned short*)alloc((size_t)B * 2048 * 2);
  unsigned short* hall0 = (unsigned short*)alloc((size_t)T * B * 512 * 2);
  unsigned short* hall1 = (unsigned short*)alloc((size_t)T * B * 1024 * 2);
  const size_t S = off;  // scratch region starts here (reused per layer)

  // ---- pick TC per layer: largest chunk fitting ws_size ----
  int TCs[3];
  for (int l = 0; l < 3; ++l) {
    const int H = Hs[l];
    const int inl = (l == 0) ? I : Hs[l - 1];
    size_t fixed = S + ((l == 0) ? pad((size_t)B * T * I * 2) : 0) +
                   pad((size_t)3 * H * inl * 2) + pad((size_t)3 * H * H * 2);
    int tc = 4;
    for (int cand = 128; cand >= 4; cand >>= 1) {
      size_t need = fixed + pad((size_t)cand * B * 3 * H * 2);
      if (need <= (size_t)(ws_size * 0.95)) { tc = cand; break; }
    }
    TCs[l] = tc;
  }

  // ---- init ----
  hipMemsetAsync(ws + hstart, 0, hend - hstart, stream);
  hipMemsetAsync(d_out, 0, (size_t)out_size * 4, stream);

  auto cast = [&](const float* s, unsigned short* d, int n) {
    cast_kernel<<<(n + 255) / 256, 256, 0, stream>>>(s, d, n);
  };

  // ---- layer phases ----
  for (int l = 0; l < 3; ++l) {
    const int H = Hs[l];
    const int inl = (l == 0) ? I : Hs[l - 1];
    const int N = 3 * H;
    const int TC = TCs[l];

    off = S;  // reset scratch
    unsigned short* xb = nullptr;
    if (l == 0) xb = (unsigned short*)alloc((size_t)B * T * I * 2);
    unsigned short* wihb = (unsigned short*)alloc((size_t)3 * H * inl * 2);
    unsigned short* whhb = (unsigned short*)alloc((size_t)3 * H * H * 2);
    unsigned short* GIc = (unsigned short*)alloc((size_t)TC * B * N * 2);

    if (l == 0) cast(x, xb, B * T * I);
    cast(Wih[l], wihb, 3 * H * inl);
    cast(Whh[l], whhb, 3 * H * H);

    const unsigned short* Ahoist = (l == 0) ? xb : (l == 1 ? hall0 : hall1);
    unsigned short* hall = (l == 0) ? hall0 : (l == 1 ? hall1 : nullptr);

    int tcsh = 0;
    while ((1 << tcsh) < TC) ++tcsh;

    for (int t0 = 0; t0 < T; t0 += TC) {
      // hoist GI for timesteps [t0, t0+TC)
      dim3 gh((unsigned)(B * TC / 64), (unsigned)(N / 64));
      if (l == 0) {
        // x rows: phys = b*T + t0 + dt; virtual rv = b*TC + dt
        hoist_kernel<<<gh, 256, 0, stream>>>(Ahoist, inl, tcsh, T, t0, TC - 1,
                                             wihb, inl, bias[l], GIc, N);
      } else {
        // hall rows: phys = t0*B + rv
        hoist_kernel<<<gh, 256, 0, stream>>>(Ahoist, inl, 31, 0, t0 * B,
                                             0x7FFFFFFF, wihb, inl, bias[l],
                                             GIc, N);
      }
      for (int t = t0; t < t0 + TC; ++t) {
        const int dt = t - t0;
        const unsigned short* giZ =
            (l == 0) ? GIc + (size_t)dt * N : GIc + (size_t)dt * B * N;
        const size_t giStride = (l == 0) ? (size_t)TC * N : (size_t)N;
        const unsigned short* giN = giZ + 2 * H;

        dim3 gzr((unsigned)(2 * H / 64));
        dim3 gn((unsigned)(H / 64));
        if (l == 0) {
          zr_kernel<512><<<gzr, 256, 0, stream>>>(hb[l], whhb, giZ, giStride,
                                                  hf[l], zbuf, rh);
          n_kernel<512><<<gn, 256, 0, stream>>>(
              rh, whhb + (size_t)2 * H * H, giN, giStride, zbuf, hf[l], hb[l],
              hall, (float*)d_out, outoff[l], mask, t);
        } else if (l == 1) {
          zr_kernel<1024><<<gzr, 256, 0, stream>>>(hb[l], whhb, giZ, giStride,
                                                   hf[l], zbuf, rh);
          n_kernel<1024><<<gn, 256, 0, stream>>>(
              rh, whhb + (size_t)2 * H * H, giN, giStride, zbuf, hf[l], hb[l],
              hall, (float*)d_out, outoff[l], mask, t);
        } else {
          zr_kernel<2048><<<gzr, 256, 0, stream>>>(hb[l], whhb, giZ, giStride,
                                                   hf[l], zbuf, rh);
          n_kernel<2048><<<gn, 256, 0, stream>>>(
              rh, whhb + (size_t)2 * H * H, giN, giStride, zbuf, hf[l], hb[l],
              hall, (float*)d_out, outoff[l], mask, t);
        }
      }
    }
  }
}

// Round 5
// 9351.923 us; speedup vs baseline: 6.7476x; 6.7476x over previous
//
#include <hip/hip_runtime.h>
#include <hip/hip_bf16.h>

// ---------------------------------------------------------------------------
// 3-layer original-paper GRU, B=128, T=128, I=512, H={512,1024,2048}.
// Round 5: diagonal (wavefront) layer pipeline + proven LDS GEMM core.
//  - Tick u: layer l computes step t=u-l (independent across layers) ->
//    2 launches/tick (zr, n), 130 ticks, ~260 launches total.
//  - Per block: M=128 (full batch), N=64, BK=128, 512 thr (8 waves: 2 row
//    halves x 4 col groups), XOR-swizzled LDS, global_load_lds x16, dbuf.
//  - Input projection fused as 2nd chunk source (R2 gemm2-style): no GI
//    buffer, no hoist kernels (R4's register-direct global fragment loads
//    were 64-way uncoalesced -> NEVER load MFMA frags from global).
//  - h state (f32 + bf16) double-buffered by tick parity to avoid the
//    intra-launch race (layer l reads h_{l-1}(t) while l-1 writes h(t+1)).
// Workspace ~76 MB (R2-proven scale).
// ---------------------------------------------------------------------------

typedef __attribute__((ext_vector_type(8))) short s16x8;
typedef __attribute__((ext_vector_type(4))) float f32x4;

#define LLDS16(g, s)                                                          \
  __builtin_amdgcn_global_load_lds(                                           \
      (const __attribute__((address_space(1))) void*)(g),                     \
      (__attribute__((address_space(3))) void*)(s), 16, 0, 0)

__device__ __forceinline__ unsigned short f2b(float f) {
  unsigned int u = __float_as_uint(f);
  unsigned int r = (u + 0x7FFFu + ((u >> 16) & 1u)) >> 16;
  return (unsigned short)r;
}
__device__ __forceinline__ float sigmoidf_(float x) {
  return 1.0f / (1.0f + __expf(-x));
}
__device__ __forceinline__ float tanhf_(float x) {
  x = fminf(fmaxf(x, -15.0f), 15.0f);
  float e = __expf(-2.0f * x);
  return (1.0f - e) / (1.0f + e);
}

struct DiagP {
  const unsigned short* xb;            // [B,T,I] bf16
  const unsigned short* wihzr[3];      // [2H, inl]
  const unsigned short* whhzr[3];      // [2H, H]
  const unsigned short* wihn[3];       // [H, inl]
  const unsigned short* whhn[3];       // [H, H]
  const float* bias[3];                // [3H]
  float* hf[3][2];                     // f32 h, 2 slots
  unsigned short* hb[3][2];            // bf16 h, 2 slots
  float* zb[3];                        // [B,H] f32
  unsigned short* rh[3];               // [B,H] bf16
  const float* mask;                   // [B,T]
  float* out;                          // [B,3584]
};

// ---- staging: 128x128 A tile (32 KB) and 64x128 B tile (16 KB), swizzled --
// LDS addr of (r, cg) = r*256B + ((cg ^ (r&15))*16B).
__device__ __forceinline__ void stageA(const unsigned short* __restrict__ g,
                                       size_t ld, int k0, unsigned short* lds) {
  const int tid = threadIdx.x;
  const int wave = tid >> 6, lane = tid & 63;
#pragma unroll
  for (int j = 0; j < 4; ++j) {
    int s = wave * 4 + j;             // 0..31, 1 KB segments (4 rows)
    int r = s * 4 + (lane >> 4);      // 0..127
    int cg = (lane & 15) ^ (r & 15);
    LLDS16(g + (size_t)r * ld + k0 + cg * 8, lds + s * 512);
  }
}
__device__ __forceinline__ void stageB(const unsigned short* __restrict__ g,
                                       size_t ld, int rowbase, int k0,
                                       unsigned short* lds) {
  const int tid = threadIdx.x;
  const int wave = tid >> 6, lane = tid & 63;
#pragma unroll
  for (int j = 0; j < 2; ++j) {
    int s = wave * 2 + j;             // 0..15
    int r = s * 4 + (lane >> 4);      // 0..63
    int cg = (lane & 15) ^ (r & 15);
    LLDS16(g + (size_t)(rowbase + r) * ld + k0 + cg * 8, lds + s * 512);
  }
}

// ---- one BK=128 chunk: wave (wg,wc) computes rows wg*64+[0,64), cols wc*16+[0,16)
__device__ __forceinline__ void cchunk(const unsigned short* Ab,
                                       const unsigned short* Bb,
                                       f32x4 acc[4]) {
  const int tid = threadIdx.x;
  const int wave = tid >> 6, lane = tid & 63;
  const int wc = wave & 3, wg = wave >> 2, quad = lane >> 4, l16 = lane & 15;
  const int brow = wc * 16 + l16;
#pragma unroll
  for (int ks = 0; ks < 4; ++ks) {
    int kg = ks * 4 + quad;
    s16x8 bv =
        *(const s16x8*)(Bb + (size_t)brow * 128 + ((kg ^ (brow & 15)) * 8));
#pragma unroll
    for (int mi = 0; mi < 4; ++mi) {
      int r = wg * 64 + mi * 16 + l16;
      s16x8 av = *(const s16x8*)(Ab + (size_t)r * 128 + ((kg ^ (r & 15)) * 8));
      acc[mi] =
          __builtin_amdgcn_mfma_f32_16x16x32_bf16(av, bv, acc[mi], 0, 0, 0);
    }
  }
}

// acc += A1@B1^T (c1 chunks) + A2@B2^T (c2 chunks); B rows at rowbase.
__device__ __forceinline__ void gemm_diag(
    const unsigned short* __restrict__ A1, size_t ldA1, int c1,
    const unsigned short* __restrict__ A2, size_t ldA2, int c2,
    const unsigned short* __restrict__ B1, size_t ldB1,
    const unsigned short* __restrict__ B2, size_t ldB2, int rowbase,
    unsigned short* As, unsigned short* Bs, f32x4 acc[4]) {
  const int total = c1 + c2;
  auto issue = [&](int c, int buf) {
    unsigned short* a = As + buf * 16384;
    unsigned short* b = Bs + buf * 8192;
    if (c < c1) {
      stageA(A1, ldA1, c << 7, a);
      stageB(B1, ldB1, rowbase, c << 7, b);
    } else {
      int k0 = (c - c1) << 7;
      stageA(A2, ldA2, k0, a);
      stageB(B2, ldB2, rowbase, k0, b);
    }
  };
  issue(0, 0);
  for (int c = 0; c < total; ++c) {
    __syncthreads();  // drains vmcnt: chunk c resident; WAR-protects buffers
    if (c + 1 < total) issue(c + 1, (c + 1) & 1);
    cchunk(As + (c & 1) * 16384, Bs + (c & 1) * 8192, acc);
  }
}

// ---- zr: all active layers' z/r gates for tick u. 112 blocks. ----
__global__ __launch_bounds__(512) void diag_zr(DiagP p, int u) {
  __shared__ unsigned short As[2 * 16384], Bs[2 * 8192];
  const int blk = blockIdx.x;
  const int l = (blk < 16) ? 0 : ((blk < 48) ? 1 : 2);
  const int nt = blk - ((l == 0) ? 0 : ((l == 1) ? 16 : 48));
  const int t = u - l;
  if (t < 0 || t >= 128) return;
  const int H = (l == 0) ? 512 : ((l == 1) ? 1024 : 2048);
  const int inl = (l == 0) ? 512 : ((l == 1) ? 512 : 1024);
  const int oldS = (u + 1) & 1;

  const unsigned short* A1 =
      (l == 0) ? p.xb + (size_t)t * 512 : p.hb[l - 1][oldS];
  const size_t ldA1 = (l == 0) ? (size_t)128 * 512 : (size_t)inl;

  f32x4 acc[4] = {};
  gemm_diag(A1, ldA1, inl >> 7, p.hb[l][oldS], (size_t)H, H >> 7, p.wihzr[l],
            (size_t)inl, p.whhzr[l], (size_t)H, nt * 64, As, Bs, acc);

  const int tid = threadIdx.x, wave = tid >> 6, lane = tid & 63;
  const int wc = wave & 3, wg = wave >> 2, quad = lane >> 4, l16 = lane & 15;
  const int colg = nt * 64 + wc * 16 + l16;
  const float bv = p.bias[l][colg];
  const bool isz = colg < H;  // uniform per block (64 | H)
  const int j = isz ? colg : colg - H;
  const float* hfo = p.hf[l][oldS];
#pragma unroll
  for (int mi = 0; mi < 4; ++mi)
#pragma unroll
    for (int r = 0; r < 4; ++r) {
      int row = wg * 64 + mi * 16 + quad * 4 + r;
      float v = acc[mi][r] + bv;
      float s = sigmoidf_(v);
      if (isz)
        p.zb[l][(size_t)row * H + j] = s;
      else
        p.rh[l][(size_t)row * H + j] = f2b(s * hfo[(size_t)row * H + j]);
    }
}

// ---- n: n gate + h update + masked out accumulation. 56 blocks. ----
__global__ __launch_bounds__(512) void diag_n(DiagP p, int u) {
  __shared__ unsigned short As[2 * 16384], Bs[2 * 8192];
  const int blk = blockIdx.x;
  const int l = (blk < 8) ? 0 : ((blk < 24) ? 1 : 2);
  const int nt = blk - ((l == 0) ? 0 : ((l == 1) ? 8 : 24));
  const int t = u - l;
  if (t < 0 || t >= 128) return;
  const int H = (l == 0) ? 512 : ((l == 1) ? 1024 : 2048);
  const int inl = (l == 0) ? 512 : ((l == 1) ? 512 : 1024);
  const int outoff = (l == 0) ? 0 : ((l == 1) ? 512 : 1536);
  const int oldS = (u + 1) & 1, newS = u & 1;

  const unsigned short* A1 =
      (l == 0) ? p.xb + (size_t)t * 512 : p.hb[l - 1][oldS];
  const size_t ldA1 = (l == 0) ? (size_t)128 * 512 : (size_t)inl;

  f32x4 acc[4] = {};
  gemm_diag(A1, ldA1, inl >> 7, p.rh[l], (size_t)H, H >> 7, p.wihn[l],
            (size_t)inl, p.whhn[l], (size_t)H, nt * 64, As, Bs, acc);

  const int tid = threadIdx.x, wave = tid >> 6, lane = tid & 63;
  const int wc = wave & 3, wg = wave >> 2, quad = lane >> 4, l16 = lane & 15;
  const int colg = nt * 64 + wc * 16 + l16;
  const float bv = p.bias[l][2 * H + colg];
  const float* hfo = p.hf[l][oldS];
  float* hfn = p.hf[l][newS];
  unsigned short* hbn = p.hb[l][newS];
#pragma unroll
  for (int mi = 0; mi < 4; ++mi)
#pragma unroll
    for (int r = 0; r < 4; ++r) {
      int row = wg * 64 + mi * 16 + quad * 4 + r;
      float v = acc[mi][r] + bv;
      float nv = tanhf_(v);
      size_t idx = (size_t)row * H + colg;
      float z = p.zb[l][idx];
      float hn = (1.0f - z) * nv + z * hfo[idx];
      hfn[idx] = hn;
      hbn[idx] = f2b(hn);
      p.out[(size_t)row * 3584 + outoff + colg] += p.mask[row * 128 + t] * hn;
    }
}

__global__ void cast_kernel(const float* __restrict__ src,
                            unsigned short* __restrict__ dst, int n) {
  int i = blockIdx.x * 256 + threadIdx.x;
  if (i < n) dst[i] = f2b(src[i]);
}

extern "C" void kernel_launch(void* const* d_in, const int* in_sizes, int n_in,
                              void* d_out, int out_size, void* d_ws,
                              size_t ws_size, hipStream_t stream) {
  const int B = 128, T = 128, I = 512;
  const int Hs[3] = {512, 1024, 2048};

  const float* x = (const float*)d_in[0];
  const float* mask = (const float*)d_in[1];
  const float* Wih[3] = {(const float*)d_in[2], (const float*)d_in[5],
                         (const float*)d_in[8]};
  const float* Whh[3] = {(const float*)d_in[3], (const float*)d_in[6],
                         (const float*)d_in[9]};
  const float* bias[3] = {(const float*)d_in[4], (const float*)d_in[7],
                          (const float*)d_in[10]};

  char* ws = (char*)d_ws;
  size_t off = 0;
  auto alloc = [&](size_t bytes) -> void* {
    void* p = ws + off;
    off = (off + bytes + 255) & ~(size_t)255;
    return p;
  };

  unsigned short* xb = (unsigned short*)alloc((size_t)B * T * I * 2);
  unsigned short *wihb[3], *whhb[3];
  for (int l = 0; l < 3; ++l) {
    int inl = (l == 0) ? I : Hs[l - 1];
    wihb[l] = (unsigned short*)alloc((size_t)3 * Hs[l] * inl * 2);
    whhb[l] = (unsigned short*)alloc((size_t)3 * Hs[l] * Hs[l] * 2);
  }
  size_t hstart = off;
  DiagP p;
  for (int l = 0; l < 3; ++l)
    for (int sl = 0; sl < 2; ++sl)
      p.hf[l][sl] = (float*)alloc((size_t)B * Hs[l] * 4);
  for (int l = 0; l < 3; ++l)
    for (int sl = 0; sl < 2; ++sl)
      p.hb[l][sl] = (unsigned short*)alloc((size_t)B * Hs[l] * 2);
  size_t hend = off;
  for (int l = 0; l < 3; ++l) p.zb[l] = (float*)alloc((size_t)B * Hs[l] * 4);
  for (int l = 0; l < 3; ++l)
    p.rh[l] = (unsigned short*)alloc((size_t)B * Hs[l] * 2);
  (void)ws_size;

  p.xb = xb;
  for (int l = 0; l < 3; ++l) {
    int inl = (l == 0) ? I : Hs[l - 1];
    p.wihzr[l] = wihb[l];
    p.wihn[l] = wihb[l] + (size_t)2 * Hs[l] * inl;
    p.whhzr[l] = whhb[l];
    p.whhn[l] = whhb[l] + (size_t)2 * Hs[l] * Hs[l];
    p.bias[l] = bias[l];
  }
  p.mask = mask;
  p.out = (float*)d_out;

  auto cast = [&](const float* s, unsigned short* d, int n) {
    cast_kernel<<<(n + 255) / 256, 256, 0, stream>>>(s, d, n);
  };
  cast(x, xb, B * T * I);
  for (int l = 0; l < 3; ++l) {
    int inl = (l == 0) ? I : Hs[l - 1];
    cast(Wih[l], wihb[l], 3 * Hs[l] * inl);
    cast(Whh[l], whhb[l], 3 * Hs[l] * Hs[l]);
  }
  hipMemsetAsync(ws + hstart, 0, hend - hstart, stream);
  hipMemsetAsync(d_out, 0, (size_t)out_size * 4, stream);

  // ---- diagonal scan: tick u covers (l, t=u-l) ----
  for (int u = 0; u < T + 2; ++u) {
    diag_zr<<<112, 512, 0, stream>>>(p, u);
    diag_n<<<56, 512, 0, stream>>>(p, u);
  }
}